// Round 1
// 70.213 us; speedup vs baseline: 1.0570x; 1.0570x over previous
//
#include <hip/hip_runtime.h>

#define HH 128
#define WW 128
#define NPX (HH * WW)
#define KK 10
#define PXB 16        // pixels per block (4x4 tile); pixel group = 16 contiguous lanes
#define LCAP 352      // per-tile gaussian list cap (expected ~126)
#define JMAX 22       // LCAP / 16 slots per lane
#define KEYC 6        // per-lane survivor keys (96/pixel cap, expected ~20)
#define SCAP (16 * KEYC)
#define SPAD (SCAP + 1)
#define ALPHA_MIN 5e-4f
#define RADIUS_K 3.8990f  // sqrt(2*ln(1/ALPHA_MIN))

typedef unsigned long long u64;
typedef unsigned int u32;

// ---- pass 0: per-gaussian derived params, computed ONCE (previously the
// radius expf ran per tile (1024x) and sincos/expf per tile-hit) ----
__global__ __launch_bounds__(256) void precompute_kernel(
    const float* __restrict__ means, const float* __restrict__ rots,
    const float* __restrict__ lscales, int nG,
    float4* __restrict__ bbox4, float4* __restrict__ prm4) {
  int g = blockIdx.x * blockDim.x + threadIdx.x;
  if (g >= nG) return;
  const float2* m2 = (const float2*)means;
  const float2* l2 = (const float2*)lscales;
  float2 mg = m2[g];
  float2 lg = l2[g];
  float smx = __expf(fmaxf(lg.x, lg.y));
  float r = fmaf(RADIUS_K * 1.01f, smx, 0.05f);
  float th = rots[g];
  float s = __sinf(th), c = __cosf(th);
  float ivx = __expf(-2.0f * lg.x);
  float ivy = __expf(-2.0f * lg.y);
  bbox4[g] = make_float4(mg.x, mg.y, r * r, mg.y);   // (mx, my, r^2, my)
  prm4[g] = make_float4(c * c * ivx + s * s * ivy,   // (a, 2b, c, mx)
                        2.0f * (c * s * (ivx - ivy)),
                        s * s * ivx + c * c * ivy, mg.x);
}

// One block = one 4x4-pixel tile; 4 waves; each pixel owned by 16 contiguous
// lanes of one wave -> all post-filter steps are wave-synchronous (no barriers).
template <int NGC, bool PRE>
__global__ __launch_bounds__(256) void splat_kernel(
    const float* __restrict__ means, const float* __restrict__ rots,
    const float* __restrict__ lscales, const float* __restrict__ cols,
    const float4* __restrict__ bbox4, const float4* __restrict__ prm4,
    int nG_rt, float* __restrict__ out) {
  const int nG = NGC > 0 ? NGC : nG_rt;
  __shared__ float4 sA[LCAP];           // (a, 2b, c, mean_x)
  __shared__ float  sMy[LCAP];
  __shared__ int    glist[LCAP];
  __shared__ float2 sbuf[PXB][SPAD];    // (alpha, id-bits)
  __shared__ float2 wbuf[PXB][KK];      // winners by rank
  __shared__ int    lcnt;

  int t = threadIdx.x;
  int lane = t & 63;
  int pl  = t >> 4;   // pixel within tile (wave w owns pixels 4w..4w+3)
  int tsl = t & 15;   // lane within pixel group
  int tile = blockIdx.x;
  int x0 = (tile & 31) << 2, y0 = (tile >> 5) << 2;
  int x = x0 | (pl & 3), y = y0 | (pl >> 2);
  float px = (float)x + 0.5f, py = (float)y + 0.5f;

  if (t == 0) lcnt = 0;
  __syncthreads();

  // ---- phase 1: conservative bbox filter, ballot-aggregated compaction ----
  const float2* m2 = (const float2*)means;
  const float2* l2 = (const float2*)lscales;
  float rx0 = (float)x0 + 0.5f, rx1 = (float)x0 + 3.5f;
  float ry0 = (float)y0 + 0.5f, ry1 = (float)y0 + 3.5f;
  for (int g = t; g < nG; g += 256) {
    bool hit;
    float4 bb;
    float2 mg, lg;
    if (PRE) {
      bb = bbox4[g];
      float cx = fminf(fmaxf(bb.x, rx0), rx1) - bb.x;
      float cy = fminf(fmaxf(bb.y, ry0), ry1) - bb.y;
      hit = (cx * cx + cy * cy <= bb.z);
    } else {
      mg = m2[g];
      lg = l2[g];
      float smx = __expf(fmaxf(lg.x, lg.y));
      float r = fmaf(RADIUS_K * 1.01f, smx, 0.05f);
      float cx = fminf(fmaxf(mg.x, rx0), rx1) - mg.x;
      float cy = fminf(fmaxf(mg.y, ry0), ry1) - mg.y;
      hit = (cx * cx + cy * cy <= r * r);
    }
    u64 mask = __ballot(hit);
    if (mask) {                                   // wave-uniform
      int leader = __ffsll((unsigned long long)mask) - 1;
      int base;
      if (lane == leader) base = atomicAdd(&lcnt, __popcll(mask));
      base = __shfl(base, leader);
      if (hit) {
        int idx = base + __popcll(mask & ((1ull << lane) - 1ull));
        if (idx < LCAP) {
          if (PRE) {
            sA[idx] = prm4[g];
            sMy[idx] = bb.w;
          } else {
            float th = rots[g];
            float s = __sinf(th), c = __cosf(th);
            float ivx = __expf(-2.0f * lg.x);
            float ivy = __expf(-2.0f * lg.y);
            sA[idx] = make_float4(c * c * ivx + s * s * ivy,
                                  2.0f * (c * s * (ivx - ivy)),
                                  s * s * ivx + c * c * ivy, mg.x);
            sMy[idx] = mg.y;
          }
          glist[idx] = g;
        }
      }
    }
  }
  __syncthreads();                                // last barrier
  int cnt = min(lcnt, LCAP);
  int jcnt = (cnt + 15) >> 4;  // BLOCK-uniform -> dead unrolled iterations
                               // skip via scalar branch (s_cbranch)

  // ---- phase 2: eval into registers ----
  float ra[JMAX];
  float mymax = 0.0f;
#pragma unroll
  for (int j = 0; j < JMAX; ++j) {
    float a = 0.0f;
    if (j < jcnt) {
      int i = tsl + (j << 4);
      if (i < cnt) {
        float4 q0 = sA[i];
        float dx = px - q0.w, dy = py - sMy[i];
        float q = fmaf(dx, fmaf(q0.y, dy, q0.x * dx), q0.z * dy * dy);
        a = __expf(-0.5f * q);
      }
    }
    ra[j] = a;
    mymax = fmaxf(mymax, a);
  }

  // ---- tau = 10th largest of the 16 lane maxes (sound lower bound on the
  // pixel's true 10th: distinct lanes -> distinct candidates). Bitonic sort
  // across the 16-lane group (10 stages) replaces the 480-op insertion net;
  // identical value -> identical survivor set -> bit-exact output. ----
  float v = mymax;
#pragma unroll
  for (int k = 2; k <= 16; k <<= 1) {
#pragma unroll
    for (int j = k >> 1; j >= 1; j >>= 1) {
      float o = __shfl_xor(v, j, 16);
      bool keepMax = (((tsl & k) == 0) == ((tsl & j) == 0));
      v = keepMax ? fmaxf(v, o) : fminf(v, o);
    }
  }
  float tau = fmaxf(__shfl(v, 9, 16), ALPHA_MIN);

  // ---- gated push via ballot compaction (no atomics, same-wave LDS) ----
  int cpx = 0;                 // group-uniform running count
  int grp = lane >> 4;
#pragma unroll
  for (int j = 0; j < JMAX; ++j) {
    if (j < jcnt) {
      bool s = ra[j] >= tau;   // implies slot valid (else ra==0 < tau)
      u64 mask = __ballot(s);
      u32 sub = (u32)((mask >> (grp * 16)) & 0xFFFFull);
      if (s) {
        int idx = cpx + __popc(sub & ((1u << tsl) - 1u));
        if (idx < SCAP)
          sbuf[pl][idx] = make_float2(ra[j], __int_as_float(glist[tsl + (j << 4)]));
      }
      cpx += __popc(sub);
    }
  }
  int scp = min(cpx, SCAP);
  int nw = min(scp, KK);

  // ---- rank-based top-10: key = (alpha_bits<<32)|~id (unique; desc key ==
  // alpha desc, id asc == exact jax.lax.top_k order). rank = #keys greater;
  // ranks are distinct 0..scp-1, so winner with rank r IS the r-th extracted
  // max of the old scheme -> identical selection and order. The broadcast
  // loop over survivors (~20) is independent-iteration (pipelinable) vs the
  // old 40-deep dependent 64-bit butterfly chain. Same-wave DS is in-order:
  // all sbuf reads precede wbuf writes precede wbuf reads in program order.
#pragma unroll
  for (int c = 0; c < KEYC; ++c) {
    if ((c << 4) < scp) {      // group-uniform; usually only c=0 (scp~20)
      int i = tsl + (c << 4);
      u64 kc = 0;
      if (i < scp) {
        float2 e = sbuf[pl][i];
        kc = ((u64)__float_as_uint(e.x) << 32) | (u32)(~(u32)__float_as_int(e.y));
      }
      int rk = 0;
      for (int s2 = 0; s2 < scp; ++s2) {
        float2 e2 = sbuf[pl][s2];                 // broadcast read
        u64 ks2 = ((u64)__float_as_uint(e2.x) << 32) |
                  (u32)(~(u32)__float_as_int(e2.y));
        rk += (kc < ks2) ? 1 : 0;
      }
      if (kc != 0 && rk < KK)
        wbuf[pl][rk] = make_float2(__uint_as_float((u32)(kc >> 32)),
                                   __int_as_float((int)(~(u32)kc)));
    }
  }

  float my_alpha = 0.0f;
  int my_id = 0;
  if (tsl < nw) {              // exactly nw winners wrote ranks 0..nw-1
    float2 e = wbuf[pl][tsl];
    my_alpha = e.x;
    my_id = __float_as_int(e.y);
  }

  // ---- composite: exclusive prefix product of (1-alpha) + butterfly sum ----
  float T = 1.0f - my_alpha;           // lanes >= nw: alpha=0 -> om=1
#pragma unroll
  for (int d = 1; d < 16; d <<= 1) {
    float u = __shfl_up(T, d, 16);
    if (tsl >= d) T *= u;
  }
  float ex = __shfl_up(T, 1, 16);
  if (tsl == 0) ex = 1.0f;
  float w = my_alpha * ex;
  float cr = 0.0f, cg = 0.0f, cb = 0.0f;
  if (my_alpha > 0.0f) {
    cr = w * cols[3 * my_id + 0];
    cg = w * cols[3 * my_id + 1];
    cb = w * cols[3 * my_id + 2];
  }
#pragma unroll
  for (int d = 1; d < 16; d <<= 1) {
    cr += __shfl_xor(cr, d);
    cg += __shfl_xor(cg, d);
    cb += __shfl_xor(cb, d);
  }
  int p = y * WW + x;
  if (tsl < 3) out[3 * p + tsl] = (tsl == 0) ? cr : ((tsl == 1) ? cg : cb);
}

extern "C" void kernel_launch(void* const* d_in, const int* in_sizes, int n_in,
                              void* d_out, int out_size, void* d_ws, size_t ws_size,
                              hipStream_t stream) {
  const float* means   = (const float*)d_in[0];
  const float* rots    = (const float*)d_in[1];
  const float* lscales = (const float*)d_in[2];
  const float* cols    = (const float*)d_in[3];
  float* out = (float*)d_out;
  int nG = in_sizes[1];  // rotations: one per gaussian

  size_t need = (size_t)nG * sizeof(float4) * 2;
  bool pre = (d_ws != nullptr) && (ws_size >= need);
  float4* bbox4 = (float4*)d_ws;
  float4* prm4 = (float4*)((char*)d_ws + (size_t)nG * sizeof(float4));

  if (pre)
    precompute_kernel<<<(nG + 255) / 256, 256, 0, stream>>>(means, rots,
                                                            lscales, nG,
                                                            bbox4, prm4);

  if (nG == 2048) {
    if (pre)
      splat_kernel<2048, true><<<NPX / PXB, 256, 0, stream>>>(
          means, rots, lscales, cols, bbox4, prm4, nG, out);
    else
      splat_kernel<2048, false><<<NPX / PXB, 256, 0, stream>>>(
          means, rots, lscales, cols, nullptr, nullptr, nG, out);
  } else {
    if (pre)
      splat_kernel<0, true><<<NPX / PXB, 256, 0, stream>>>(
          means, rots, lscales, cols, bbox4, prm4, nG, out);
    else
      splat_kernel<0, false><<<NPX / PXB, 256, 0, stream>>>(
          means, rots, lscales, cols, nullptr, nullptr, nG, out);
  }
}